// Round 18
// baseline (173.048 us; speedup 1.0000x reference)
//
#include <hip/hip_runtime.h>
#include <cstdint>
#include <cstddef>

#define NTOK 2048
#define DMODEL 1024
#define HD 64
#define MROWS 8192

using f16x8  = __attribute__((ext_vector_type(8))) _Float16;
using f16x4  = __attribute__((ext_vector_type(4))) _Float16;
using f32x4  = __attribute__((ext_vector_type(4))) float;
using f32x16 = __attribute__((ext_vector_type(16))) float;
using u32x4  = __attribute__((ext_vector_type(4))) unsigned int;

#define Z16 {0.f,0.f,0.f,0.f,0.f,0.f,0.f,0.f,0.f,0.f,0.f,0.f,0.f,0.f,0.f,0.f}

__device__ __forceinline__ unsigned pkf16(float a, float b) {
  return __builtin_bit_cast(unsigned, __builtin_amdgcn_cvt_pkrtz(a, b));
}
__device__ __forceinline__ void plswap(unsigned &a, unsigned &b) {
  auto r = __builtin_amdgcn_permlane32_swap(a, b, false, false);
  a = r[0]; b = r[1];
}
__device__ __forceinline__ float fexp2(float x) {
  return __builtin_amdgcn_exp2f(x);
}
__device__ __forceinline__ float fmax3(float a, float b, float c) {
  return fmaxf(fmaxf(a, b), c);
}

// ---------------------------------------------------------------------------
// f32 -> f16 convert (x)
// ---------------------------------------------------------------------------
__global__ __launch_bounds__(256) void cvt_f32_f16(const float* __restrict__ in,
                                                   _Float16* __restrict__ out,
                                                   int n4, float scale) {
  int idx = blockIdx.x * 256 + threadIdx.x;
  if (idx < n4) {
    float4 v = reinterpret_cast<const float4*>(in)[idx];
    f16x4 o;
    o.x = (_Float16)(v.x * scale); o.y = (_Float16)(v.y * scale);
    o.z = (_Float16)(v.z * scale); o.w = (_Float16)(v.w * scale);
    reinterpret_cast<f16x4*>(out)[idx] = o;
  }
}

// both weight matrices in one launch; log2(e) folded into Wq
__global__ __launch_bounds__(256) void cvt_w(const float* __restrict__ Wk,
                                             const float* __restrict__ Wq,
                                             _Float16* __restrict__ Wkb,
                                             _Float16* __restrict__ Wqb) {
  const int idx = blockIdx.x * 256 + threadIdx.x;
  const float* in = blockIdx.y ? Wq : Wk;
  _Float16* out = blockIdx.y ? Wqb : Wkb;
  const float scale = blockIdx.y ? 1.4426950408889634f : 1.0f;
  float4 v = reinterpret_cast<const float4*>(in)[idx];
  f16x4 o;
  o.x = (_Float16)(v.x * scale); o.y = (_Float16)(v.y * scale);
  o.z = (_Float16)(v.z * scale); o.w = (_Float16)(v.w * scale);
  reinterpret_cast<f16x4*>(out)[idx] = o;
}

// ---------------------------------------------------------------------------
// f16 MFMA GEMM with FUSED PACK epilogue (r17, unchanged). z=0 -> Kp + KTp
// (direct from LDS tile), z=1 -> Qp.
// ---------------------------------------------------------------------------
#define GLDS16(g, l) __builtin_amdgcn_global_load_lds(                      \
    (const __attribute__((address_space(1))) void*)(g),                     \
    (__attribute__((address_space(3))) void*)(l), 16, 0, 0)

__global__ __launch_bounds__(256) void gemm_pack_f16(
    const _Float16* __restrict__ X,
    const _Float16* __restrict__ Wk,
    const _Float16* __restrict__ Wq,
    _Float16* __restrict__ Kp,
    _Float16* __restrict__ Qp,
    _Float16* __restrict__ KTp,
    int emitKT) {
  const bool isQ = blockIdx.z != 0;
  const _Float16* __restrict__ W = isQ ? Wq : Wk;

  __shared__ _Float16 arena[17408];
  _Float16* As = arena;           // [2][4096]
  _Float16* Bs = arena + 8192;    // [2][4096]

  const int tid = threadIdx.x;
  const int lane = tid & 63;
  const int w = tid >> 6;
  const int m0 = blockIdx.x * 128;
  const int o0 = blockIdx.y * 128;

  const int srow = w * 32 + (lane >> 2);
  const int scol = (lane & 3) * 8;
  const _Float16* xsrc = X + (size_t)(m0 + srow) * DMODEL + scol;
  const _Float16* wsrc = W + (size_t)(o0 + srow) * DMODEL + scol;

  const int wr = w >> 1, wc = w & 1;
  const int arow = lane & 15, kg = lane >> 4;
  const int l31 = lane & 31, hi8 = (lane >> 5) * 8;

  f32x4 zero = {0.f, 0.f, 0.f, 0.f};
  f32x4 acc[4][4];
#pragma unroll
  for (int mi = 0; mi < 4; ++mi)
#pragma unroll
    for (int ni = 0; ni < 4; ++ni) acc[mi][ni] = zero;

  GLDS16(xsrc,               &As[(w * 32) * 32]);
  GLDS16(xsrc + 16 * DMODEL, &As[(w * 32 + 16) * 32]);
  GLDS16(wsrc,               &Bs[(w * 32) * 32]);
  GLDS16(wsrc + 16 * DMODEL, &Bs[(w * 32 + 16) * 32]);

  for (int kt = 0; kt < 32; ++kt) {
    __syncthreads();
    if (kt + 1 < 32) {
      const int ko = (kt + 1) * 32;
      const int bo = ((kt + 1) & 1) * 4096;
      GLDS16(xsrc + ko,               &As[bo + (w * 32) * 32]);
      GLDS16(xsrc + ko + 16 * DMODEL, &As[bo + (w * 32 + 16) * 32]);
      GLDS16(wsrc + ko,               &Bs[bo + (w * 32) * 32]);
      GLDS16(wsrc + ko + 16 * DMODEL, &Bs[bo + (w * 32 + 16) * 32]);
    }
    const int bo = (kt & 1) * 4096;
    f16x8 af[4], bfr[4];
#pragma unroll
    for (int mi = 0; mi < 4; ++mi)
      af[mi] = *reinterpret_cast<const f16x8*>(
          &As[bo + (wr * 64 + mi * 16 + arow) * 32 + kg * 8]);
#pragma unroll
    for (int ni = 0; ni < 4; ++ni)
      bfr[ni] = *reinterpret_cast<const f16x8*>(
          &Bs[bo + (wc * 64 + ni * 16 + arow) * 32 + kg * 8]);
#pragma unroll
    for (int mi = 0; mi < 4; ++mi)
#pragma unroll
      for (int ni = 0; ni < 4; ++ni)
        acc[mi][ni] = __builtin_amdgcn_mfma_f32_16x16x32_f16(
            af[mi], bfr[ni], acc[mi][ni], 0, 0, 0);
  }

  __syncthreads();
  _Float16* T = arena;             // [128][136]
#pragma unroll
  for (int mi = 0; mi < 4; ++mi)
#pragma unroll
    for (int ni = 0; ni < 4; ++ni)
#pragma unroll
      for (int r = 0; r < 4; ++r)
        T[(wr * 64 + mi * 16 + kg * 4 + r) * 136 + wc * 64 + ni * 16 + arow] =
            (_Float16)acc[mi][ni][r];
  __syncthreads();

  const int b = m0 >> 11;
  _Float16* RowDst = isQ ? Qp : Kp;
#pragma unroll
  for (int k = 0; k < 8; ++k) {
    const int c = w * 8 + k;
    const int hl = c >> 4, rtl = (c >> 2) & 3, ks = c & 3;
    f16x8 v = *reinterpret_cast<const f16x8*>(
        &T[(rtl * 32 + l31) * 136 + hl * 64 + ks * 16 + hi8]);
    const int bh = b * 16 + (o0 >> 6) + hl;
    const int rt = ((m0 & 2047) >> 5) + rtl;
    const size_t ch = ((size_t)(bh * 64 + rt) * 4 + ks) * 512 + (size_t)lane * 8;
    *reinterpret_cast<f16x8*>(&RowDst[ch]) = v;
  }

  if (!isQ && emitKT) {
#pragma unroll
    for (int k = 0; k < 8; ++k) {
      const int c = w * 8 + k;                 // (hl, jtl, ds, ks)
      const int hl = c >> 4, jtl = (c >> 3) & 1, ds = (c >> 2) & 1, ks = c & 3;
      const int row0 = jtl * 64 + ks * 16 + (lane >> 5) * 8;
      const int col = hl * 64 + ds * 32 + l31;
      f16x8 v;
#pragma unroll
      for (int e = 0; e < 8; ++e) v[e] = T[(row0 + e) * 136 + col];
      const int bh = b * 16 + (o0 >> 6) + hl;
      const int jt = ((m0 & 2047) >> 6) + jtl;
      const size_t ch =
          (((size_t)(bh * 32 + jt) * 2 + ds) * 4 + ks) * 512 + (size_t)lane * 8;
      *reinterpret_cast<f16x8*>(&KTp[ch]) = v;
    }
  }
}

// ---------------------------------------------------------------------------
// pack_kt (fallback when ws too small to give KTp its own region)
// ---------------------------------------------------------------------------
__global__ __launch_bounds__(256) void pack_kt(
    const _Float16* __restrict__ Kp,
    _Float16* __restrict__ KTp) {
  const int blk = blockIdx.x;
  const int bh = blk >> 5;
  const int t64 = blk & 31;
  const int tid = threadIdx.x;
  const int l = tid & 63;

  __shared__ _Float16 t[64][72];
#pragma unroll
  for (int pass = 0; pass < 2; ++pass) {
    const int idx = pass * 4 + (tid >> 6);
    const int rs = idx >> 2, ks = idx & 3;
    f16x8 v = *reinterpret_cast<const f16x8*>(
        &Kp[((size_t)(bh * 64 + t64 * 2 + rs) * 4 + ks) * 512 + (size_t)l * 8]);
    *reinterpret_cast<f16x8*>(&t[rs * 32 + (l & 31)][ks * 16 + (l >> 5) * 8]) = v;
  }
  __syncthreads();
#pragma unroll
  for (int pass = 0; pass < 2; ++pass) {
    const int idx = pass * 4 + (tid >> 6);
    const int ds = idx >> 2, ks = idx & 3;
    const int row0 = ks * 16 + (l >> 5) * 8;
    const int col = ds * 32 + (l & 31);
    f16x8 v;
#pragma unroll
    for (int e = 0; e < 8; ++e) v[e] = t[row0 + e][col];
    const size_t ch = (((size_t)(bh * 32 + t64) * 2 + ds) * 4 + ks) * 512 + (size_t)l * 8;
    *reinterpret_cast<f16x8*>(&KTp[ch]) = v;
  }
}

// ---------------------------------------------------------------------------
// Swapped-operand MFMA flash attention, SPLIT-J (flash merge).
// r17 analysis: VALUBusy includes MFMA on gfx950 (gfx94x formula fallback),
// so true VALU-only ~= 29% ~= 32us; MFMA ~32us; the other ~47us of 111 is
// LATENCY at 3 waves/SIMD (occupancy 35.8% = reg-capped at ~170 regs under
// launch_bounds(256,3)). True live set ~120-130 regs -> (256,4) should fit
// (r14's disaster was forcing 85 regs; 128 is at the live set, not below).
// Trim: KT loads moved from after-QK to before-PV (-16 regs across the
// softmax window); the extra resident wave covers their latency instead.
// ---------------------------------------------------------------------------
__global__ __launch_bounds__(256, 4) void attn_mfma(
    const _Float16* __restrict__ Kp,
    const _Float16* __restrict__ Qp,
    const _Float16* __restrict__ KTp,
    float* __restrict__ out) {
  const int bid = blockIdx.x;
  const int myid = (bid & 7) * 256 + (bid >> 3);   // 2048 blocks, bijective
  const int bh = myid >> 5;                        // 32 blocks per head
  const int itile = myid & 31;
  const int tid = threadIdx.x, lane = tid & 63, w = tid >> 6;
  const int l31 = lane & 31;
  const int hi = lane >> 5;
  const int i_sub = w & 1;
  const int jh = w >> 1;
  const int i0 = itile * 64 + i_sub * 32;

  const _Float16* kpp  = Kp  + (size_t)bh * 131072 + lane * 8;
  const _Float16* qpp  = Qp  + (size_t)bh * 131072 + lane * 8;
  const _Float16* ktpp = KTp + (size_t)bh * 131072 + lane * 8;

  __shared__ float scl[4][32];
  __shared__ float mM[2][2][32];
  __shared__ float lsM[2][2][32];
  __shared__ float obuf[2][32][64];

  f16x8 kbf[4];
#pragma unroll
  for (int ks = 0; ks < 4; ++ks)
    kbf[ks] = *reinterpret_cast<const f16x8*>(
        kpp + ((size_t)(i0 >> 5) * 4 + ks) * 512);

  const f32x16 z16v = Z16;
  f32x16 o0 = z16v, o1 = z16v;
  float mreg = -1e30f, ls = 0.f;

  const int jt0 = jh * 32;
  for (int jt = jt0; jt < jt0 + 32; ++jt) {
    f16x8 q[4];
#pragma unroll
    for (int ks = 0; ks < 4; ++ks)
      q[ks] = *reinterpret_cast<const f16x8*>(qpp + ((size_t)jt * 4 + ks) * 512);

    f32x16 s = z16v;
    __builtin_amdgcn_s_setprio(1);
#pragma unroll
    for (int ks = 0; ks < 4; ++ks)
      s = __builtin_amdgcn_mfma_f32_32x32x16_f16(q[ks], kbf[ks], s, 0, 0, 0);
    __builtin_amdgcn_s_setprio(0);

    // row max via v_max3
    float t0 = fmax3(s[0], s[1], s[2]);
    float t1 = fmax3(s[3], s[4], s[5]);
    float t2 = fmax3(s[6], s[7], s[8]);
    float t3 = fmax3(s[9], s[10], s[11]);
    float t4 = fmax3(s[12], s[13], s[14]);
    float pm = fmaxf(fmax3(t0, t1, t2), fmax3(t3, t4, s[15]));
    pm = fmaxf(pm, __shfl_xor(pm, 32));

    if (!__all(pm <= mreg + 8.0f)) {
      const float mn = fmaxf(mreg, pm);
      const float sc = fexp2(mreg - mn);
      ls *= sc;
      mreg = mn;
      scl[w][l31] = sc;
#pragma unroll
      for (int r = 0; r < 16; ++r) {
        const int il = (r & 3) + 8 * (r >> 2) + 4 * hi;
        const float scr = scl[w][il];
        o0[r] *= scr; o1[r] *= scr;
      }
    }

#pragma unroll
    for (int r = 0; r < 16; ++r) s[r] = fexp2(s[r] - mreg);
    {
      float l0 = (s[0] + s[4]) + (s[8] + s[12]);
      float l1 = (s[1] + s[5]) + (s[9] + s[13]);
      float l2 = (s[2] + s[6]) + (s[10] + s[14]);
      float l3 = (s[3] + s[7]) + (s[11] + s[15]);
      ls += (l0 + l1) + (l2 + l3);
    }

    f16x8 pfr[2];
    {
      unsigned a0 = pkf16(s[0], s[1]),  b0 = pkf16(s[4], s[5]);
      unsigned a1 = pkf16(s[2], s[3]),  b1 = pkf16(s[6], s[7]);
      plswap(a0, b0); plswap(a1, b1);
      u32x4 t; t[0] = a0; t[1] = a1; t[2] = b0; t[3] = b1;
      pfr[0] = __builtin_bit_cast(f16x8, t);
      unsigned a2 = pkf16(s[8], s[9]),   b2 = pkf16(s[12], s[13]);
      unsigned a3 = pkf16(s[10], s[11]), b3 = pkf16(s[14], s[15]);
      plswap(a2, b2); plswap(a3, b3);
      t[0] = a2; t[1] = a3; t[2] = b2; t[3] = b3;
      pfr[1] = __builtin_bit_cast(f16x8, t);
    }

    // KT loads here (post-softmax): -16 regs across the softmax window;
    // latency covered by the extra resident wave at (256,4).
    f16x8 kt0[2], kt1[2];
    {
      const size_t base = ((size_t)(jt >> 1) * 8 + (size_t)(jt & 1) * 2) * 512;
#pragma unroll
      for (int kk = 0; kk < 2; ++kk) {
        kt0[kk] = *reinterpret_cast<const f16x8*>(ktpp + base + (size_t)kk * 512);
        kt1[kk] = *reinterpret_cast<const f16x8*>(ktpp + base + (size_t)(4 + kk) * 512);
      }
    }

    __builtin_amdgcn_s_setprio(1);
#pragma unroll
    for (int kk = 0; kk < 2; ++kk) {
      o0 = __builtin_amdgcn_mfma_f32_32x32x16_f16(pfr[kk], kt0[kk], o0, 0, 0, 0);
      o1 = __builtin_amdgcn_mfma_f32_32x32x16_f16(pfr[kk], kt1[kk], o1, 0, 0, 0);
    }
    __builtin_amdgcn_s_setprio(0);
  }

  // ---- flash merge of the two j-halves ----
  mM[i_sub][jh][l31]  = mreg;
  lsM[i_sub][jh][l31] = ls + __shfl_xor(ls, 32);
  __syncthreads();

  if (jh == 1) {
#pragma unroll
    for (int r = 0; r < 16; ++r) {
      const int il = (r & 3) + 8 * (r >> 2) + 4 * hi;
      const float mS = fmaxf(mM[i_sub][0][il], mM[i_sub][1][il]);
      const float f = fexp2(mM[i_sub][1][il] - mS);
      obuf[i_sub][r][lane]      = o0[r] * f;
      obuf[i_sub][r + 16][lane] = o1[r] * f;
    }
  }
  __syncthreads();
  if (jh == 0) {
#pragma unroll
    for (int r = 0; r < 16; ++r) {
      const int il = (r & 3) + 8 * (r >> 2) + 4 * hi;
      const float mA = mM[i_sub][0][il], mB = mM[i_sub][1][il];
      const float mS = fmaxf(mA, mB);
      const float fA = fexp2(mA - mS);
      const float fB = fexp2(mB - mS);
      const float lsS = lsM[i_sub][0][il] * fA + lsM[i_sub][1][il] * fB;
      const float inv = 1.0f / lsS;
      const size_t rowb = ((size_t)bh * NTOK + i0 + il) * HD;
      out[rowb + l31]      = (o0[r] * fA + obuf[i_sub][r][lane]) * inv;
      out[rowb + 32 + l31] = (o1[r] * fA + obuf[i_sub][r + 16][lane]) * inv;
    }
  }
}

extern "C" void kernel_launch(void* const* d_in, const int* in_sizes, int n_in,
                              void* d_out, int out_size, void* d_ws, size_t ws_size,
                              hipStream_t stream) {
  const float* x  = (const float*)d_in[0];
  const float* Wk = (const float*)d_in[1];
  const float* Wq = (const float*)d_in[2];
  // d_in[3] (Wv) is dead code in the reference — never read.
  float* out = (float*)d_out;

  // Preferred ws layout (f16 elems, 71.3 MB):
  //   xb[8388608] Wkb[1048576] Wqb[1048576] Kp[8388608] Qp[8388608] KTp[8388608]
  // Fallback (54.5 MB, r15 schedule): KTp aliases xb, separate pack_kt pass.
  _Float16* xb  = (_Float16*)d_ws;
  _Float16* Wkb = xb + (size_t)8388608;
  _Float16* Wqb = Wkb + (size_t)1048576;
  _Float16* Kp  = Wqb + (size_t)1048576;
  _Float16* Qp  = Kp + (size_t)8388608;
  const bool fuseKT = ws_size >= (size_t)71303168;
  _Float16* KTp = fuseKT ? (Qp + (size_t)8388608) : xb;

  cvt_f32_f16<<<8192, 256, 0, stream>>>(x, xb, 2097152, 1.0f);
  cvt_w<<<dim3(1024, 2), 256, 0, stream>>>(Wk, Wq, Wkb, Wqb);

  dim3 ggrid(MROWS / 128, DMODEL / 128, 2);   // z=0 -> Kp(+KTp), z=1 -> Qp
  gemm_pack_f16<<<ggrid, 256, 0, stream>>>(xb, Wkb, Wqb, Kp, Qp, KTp,
                                           fuseKT ? 1 : 0);

  if (!fuseKT) pack_kt<<<2048, 256, 0, stream>>>(Kp, KTp);

  attn_mfma<<<2048, 256, 0, stream>>>(Kp, Qp, KTp, out);
}

// Round 19
// 167.994 us; speedup vs baseline: 1.0301x; 1.0301x over previous
//
#include <hip/hip_runtime.h>
#include <cstdint>
#include <cstddef>

#define NTOK 2048
#define DMODEL 1024
#define HD 64
#define MROWS 8192

using f16x8  = __attribute__((ext_vector_type(8))) _Float16;
using f16x4  = __attribute__((ext_vector_type(4))) _Float16;
using f32x4  = __attribute__((ext_vector_type(4))) float;
using f32x16 = __attribute__((ext_vector_type(16))) float;
using u32x4  = __attribute__((ext_vector_type(4))) unsigned int;

#define Z16 {0.f,0.f,0.f,0.f,0.f,0.f,0.f,0.f,0.f,0.f,0.f,0.f,0.f,0.f,0.f,0.f}

__device__ __forceinline__ unsigned pkf16(float a, float b) {
  return __builtin_bit_cast(unsigned, __builtin_amdgcn_cvt_pkrtz(a, b));
}
__device__ __forceinline__ void plswap(unsigned &a, unsigned &b) {
  auto r = __builtin_amdgcn_permlane32_swap(a, b, false, false);
  a = r[0]; b = r[1];
}
__device__ __forceinline__ float fexp2(float x) {
  return __builtin_amdgcn_exp2f(x);
}
__device__ __forceinline__ float fmax3(float a, float b, float c) {
  return fmaxf(fmaxf(a, b), c);
}

// ---------------------------------------------------------------------------
// Fused f32->f16 convert: blocks [0,8192) convert x (scale 1);
// blocks [8192,9216) convert Wk; [9216,10240) convert Wq (log2e folded).
// One launch instead of two (saves a dispatch + gap).
// ---------------------------------------------------------------------------
__global__ __launch_bounds__(256) void cvt_all(const float* __restrict__ x,
                                               const float* __restrict__ Wk,
                                               const float* __restrict__ Wq,
                                               _Float16* __restrict__ xb,
                                               _Float16* __restrict__ Wkb,
                                               _Float16* __restrict__ Wqb) {
  const int blk = blockIdx.x;
  const float* in;
  _Float16* out;
  float scale;
  int idx;
  if (blk < 8192) {
    in = x; out = xb; scale = 1.0f;
    idx = blk * 256 + threadIdx.x;
  } else if (blk < 9216) {
    in = Wk; out = Wkb; scale = 1.0f;
    idx = (blk - 8192) * 256 + threadIdx.x;
  } else {
    in = Wq; out = Wqb; scale = 1.4426950408889634f;
    idx = (blk - 9216) * 256 + threadIdx.x;
  }
  float4 v = reinterpret_cast<const float4*>(in)[idx];
  f16x4 o;
  o.x = (_Float16)(v.x * scale); o.y = (_Float16)(v.y * scale);
  o.z = (_Float16)(v.z * scale); o.w = (_Float16)(v.w * scale);
  reinterpret_cast<f16x4*>(out)[idx] = o;
}

// ---------------------------------------------------------------------------
// f16 MFMA GEMM with FUSED PACK epilogue (r17, unchanged). z=0 -> Kp + KTp
// (direct from LDS tile), z=1 -> Qp.
//   Qp/Kp[bh][rt(32rows)][ks][lane][8] = Y_head[rt*32+(l&31)][ks*16+(l>>5)*8+e]
//   KTp[bh][jt(64rows)][ds][ks][lane][8]
//     = K_head[jt*64+ks*16+(l>>5)*8+e][ds*32+(l&31)]
// ---------------------------------------------------------------------------
#define GLDS16(g, l) __builtin_amdgcn_global_load_lds(                      \
    (const __attribute__((address_space(1))) void*)(g),                     \
    (__attribute__((address_space(3))) void*)(l), 16, 0, 0)

__global__ __launch_bounds__(256) void gemm_pack_f16(
    const _Float16* __restrict__ X,
    const _Float16* __restrict__ Wk,
    const _Float16* __restrict__ Wq,
    _Float16* __restrict__ Kp,
    _Float16* __restrict__ Qp,
    _Float16* __restrict__ KTp,
    int emitKT) {
  const bool isQ = blockIdx.z != 0;
  const _Float16* __restrict__ W = isQ ? Wq : Wk;

  __shared__ _Float16 arena[17408];
  _Float16* As = arena;           // [2][4096]
  _Float16* Bs = arena + 8192;    // [2][4096]

  const int tid = threadIdx.x;
  const int lane = tid & 63;
  const int w = tid >> 6;
  const int m0 = blockIdx.x * 128;
  const int o0 = blockIdx.y * 128;

  const int srow = w * 32 + (lane >> 2);
  const int scol = (lane & 3) * 8;
  const _Float16* xsrc = X + (size_t)(m0 + srow) * DMODEL + scol;
  const _Float16* wsrc = W + (size_t)(o0 + srow) * DMODEL + scol;

  const int wr = w >> 1, wc = w & 1;
  const int arow = lane & 15, kg = lane >> 4;
  const int l31 = lane & 31, hi8 = (lane >> 5) * 8;

  f32x4 zero = {0.f, 0.f, 0.f, 0.f};
  f32x4 acc[4][4];
#pragma unroll
  for (int mi = 0; mi < 4; ++mi)
#pragma unroll
    for (int ni = 0; ni < 4; ++ni) acc[mi][ni] = zero;

  GLDS16(xsrc,               &As[(w * 32) * 32]);
  GLDS16(xsrc + 16 * DMODEL, &As[(w * 32 + 16) * 32]);
  GLDS16(wsrc,               &Bs[(w * 32) * 32]);
  GLDS16(wsrc + 16 * DMODEL, &Bs[(w * 32 + 16) * 32]);

  for (int kt = 0; kt < 32; ++kt) {
    __syncthreads();
    if (kt + 1 < 32) {
      const int ko = (kt + 1) * 32;
      const int bo = ((kt + 1) & 1) * 4096;
      GLDS16(xsrc + ko,               &As[bo + (w * 32) * 32]);
      GLDS16(xsrc + ko + 16 * DMODEL, &As[bo + (w * 32 + 16) * 32]);
      GLDS16(wsrc + ko,               &Bs[bo + (w * 32) * 32]);
      GLDS16(wsrc + ko + 16 * DMODEL, &Bs[bo + (w * 32 + 16) * 32]);
    }
    const int bo = (kt & 1) * 4096;
    f16x8 af[4], bfr[4];
#pragma unroll
    for (int mi = 0; mi < 4; ++mi)
      af[mi] = *reinterpret_cast<const f16x8*>(
          &As[bo + (wr * 64 + mi * 16 + arow) * 32 + kg * 8]);
#pragma unroll
    for (int ni = 0; ni < 4; ++ni)
      bfr[ni] = *reinterpret_cast<const f16x8*>(
          &Bs[bo + (wc * 64 + ni * 16 + arow) * 32 + kg * 8]);
#pragma unroll
    for (int mi = 0; mi < 4; ++mi)
#pragma unroll
      for (int ni = 0; ni < 4; ++ni)
        acc[mi][ni] = __builtin_amdgcn_mfma_f32_16x16x32_f16(
            af[mi], bfr[ni], acc[mi][ni], 0, 0, 0);
  }

  __syncthreads();
  _Float16* T = arena;             // [128][136]
#pragma unroll
  for (int mi = 0; mi < 4; ++mi)
#pragma unroll
    for (int ni = 0; ni < 4; ++ni)
#pragma unroll
      for (int r = 0; r < 4; ++r)
        T[(wr * 64 + mi * 16 + kg * 4 + r) * 136 + wc * 64 + ni * 16 + arow] =
            (_Float16)acc[mi][ni][r];
  __syncthreads();

  const int b = m0 >> 11;
  _Float16* RowDst = isQ ? Qp : Kp;
#pragma unroll
  for (int k = 0; k < 8; ++k) {
    const int c = w * 8 + k;
    const int hl = c >> 4, rtl = (c >> 2) & 3, ks = c & 3;
    f16x8 v = *reinterpret_cast<const f16x8*>(
        &T[(rtl * 32 + l31) * 136 + hl * 64 + ks * 16 + hi8]);
    const int bh = b * 16 + (o0 >> 6) + hl;
    const int rt = ((m0 & 2047) >> 5) + rtl;
    const size_t ch = ((size_t)(bh * 64 + rt) * 4 + ks) * 512 + (size_t)lane * 8;
    *reinterpret_cast<f16x8*>(&RowDst[ch]) = v;
  }

  if (!isQ && emitKT) {
#pragma unroll
    for (int k = 0; k < 8; ++k) {
      const int c = w * 8 + k;                 // (hl, jtl, ds, ks)
      const int hl = c >> 4, jtl = (c >> 3) & 1, ds = (c >> 2) & 1, ks = c & 3;
      const int row0 = jtl * 64 + ks * 16 + (lane >> 5) * 8;
      const int col = hl * 64 + ds * 32 + l31;
      f16x8 v;
#pragma unroll
      for (int e = 0; e < 8; ++e) v[e] = T[(row0 + e) * 136 + col];
      const int bh = b * 16 + (o0 >> 6) + hl;
      const int jt = ((m0 & 2047) >> 6) + jtl;
      const size_t ch =
          (((size_t)(bh * 32 + jt) * 2 + ds) * 4 + ks) * 512 + (size_t)lane * 8;
      *reinterpret_cast<f16x8*>(&KTp[ch]) = v;
    }
  }
}

// ---------------------------------------------------------------------------
// pack_kt (fallback when ws too small to give KTp its own region)
// ---------------------------------------------------------------------------
__global__ __launch_bounds__(256) void pack_kt(
    const _Float16* __restrict__ Kp,
    _Float16* __restrict__ KTp) {
  const int blk = blockIdx.x;
  const int bh = blk >> 5;
  const int t64 = blk & 31;
  const int tid = threadIdx.x;
  const int l = tid & 63;

  __shared__ _Float16 t[64][72];
#pragma unroll
  for (int pass = 0; pass < 2; ++pass) {
    const int idx = pass * 4 + (tid >> 6);
    const int rs = idx >> 2, ks = idx & 3;
    f16x8 v = *reinterpret_cast<const f16x8*>(
        &Kp[((size_t)(bh * 64 + t64 * 2 + rs) * 4 + ks) * 512 + (size_t)l * 8]);
    *reinterpret_cast<f16x8*>(&t[rs * 32 + (l & 31)][ks * 16 + (l >> 5) * 8]) = v;
  }
  __syncthreads();
#pragma unroll
  for (int pass = 0; pass < 2; ++pass) {
    const int idx = pass * 4 + (tid >> 6);
    const int ds = idx >> 2, ks = idx & 3;
    const int row0 = ks * 16 + (l >> 5) * 8;
    const int col = ds * 32 + (l & 31);
    f16x8 v;
#pragma unroll
    for (int e = 0; e < 8; ++e) v[e] = t[row0 + e][col];
    const size_t ch = (((size_t)(bh * 32 + t64) * 2 + ds) * 4 + ks) * 512 + (size_t)l * 8;
    *reinterpret_cast<f16x8*>(&KTp[ch]) = v;
  }
}

// ---------------------------------------------------------------------------
// Swapped-operand MFMA flash attention, SPLIT-J (flash merge) — EXACT r17
// configuration (best measured attn: 110.0-111.6 us). r18's (256,4) +
// KT-load-after-softmax regressed (occupancy unchanged at 3 waves/SIMD,
// KT latency serialized): both reverted. The attn inner loop is at a
// stable local optimum; further gains need a deep-pipeline structural port.
// ---------------------------------------------------------------------------
__global__ __launch_bounds__(256, 3) void attn_mfma(
    const _Float16* __restrict__ Kp,
    const _Float16* __restrict__ Qp,
    const _Float16* __restrict__ KTp,
    float* __restrict__ out) {
  const int bid = blockIdx.x;
  const int myid = (bid & 7) * 256 + (bid >> 3);   // 2048 blocks, bijective
  const int bh = myid >> 5;                        // 32 blocks per head
  const int itile = myid & 31;
  const int tid = threadIdx.x, lane = tid & 63, w = tid >> 6;
  const int l31 = lane & 31;
  const int hi = lane >> 5;
  const int i_sub = w & 1;
  const int jh = w >> 1;
  const int i0 = itile * 64 + i_sub * 32;

  const _Float16* kpp  = Kp  + (size_t)bh * 131072 + lane * 8;
  const _Float16* qpp  = Qp  + (size_t)bh * 131072 + lane * 8;
  const _Float16* ktpp = KTp + (size_t)bh * 131072 + lane * 8;

  __shared__ float scl[4][32];
  __shared__ float mM[2][2][32];
  __shared__ float lsM[2][2][32];
  __shared__ float obuf[2][32][64];

  f16x8 kbf[4];
#pragma unroll
  for (int ks = 0; ks < 4; ++ks)
    kbf[ks] = *reinterpret_cast<const f16x8*>(
        kpp + ((size_t)(i0 >> 5) * 4 + ks) * 512);

  const f32x16 z16v = Z16;
  f32x16 o0 = z16v, o1 = z16v;
  float mreg = -1e30f, ls = 0.f;

  const int jt0 = jh * 32;
  for (int jt = jt0; jt < jt0 + 32; ++jt) {
    f16x8 q[4];
#pragma unroll
    for (int ks = 0; ks < 4; ++ks)
      q[ks] = *reinterpret_cast<const f16x8*>(qpp + ((size_t)jt * 4 + ks) * 512);

    f32x16 s = z16v;
    __builtin_amdgcn_s_setprio(1);
#pragma unroll
    for (int ks = 0; ks < 4; ++ks)
      s = __builtin_amdgcn_mfma_f32_32x32x16_f16(q[ks], kbf[ks], s, 0, 0, 0);
    __builtin_amdgcn_s_setprio(0);

    f16x8 kt0[2], kt1[2];
    {
      const size_t base = ((size_t)(jt >> 1) * 8 + (size_t)(jt & 1) * 2) * 512;
#pragma unroll
      for (int kk = 0; kk < 2; ++kk) {
        kt0[kk] = *reinterpret_cast<const f16x8*>(ktpp + base + (size_t)kk * 512);
        kt1[kk] = *reinterpret_cast<const f16x8*>(ktpp + base + (size_t)(4 + kk) * 512);
      }
    }

    // row max via v_max3
    float t0 = fmax3(s[0], s[1], s[2]);
    float t1 = fmax3(s[3], s[4], s[5]);
    float t2 = fmax3(s[6], s[7], s[8]);
    float t3 = fmax3(s[9], s[10], s[11]);
    float t4 = fmax3(s[12], s[13], s[14]);
    float pm = fmaxf(fmax3(t0, t1, t2), fmax3(t3, t4, s[15]));
    pm = fmaxf(pm, __shfl_xor(pm, 32));

    if (!__all(pm <= mreg + 8.0f)) {
      const float mn = fmaxf(mreg, pm);
      const float sc = fexp2(mreg - mn);
      ls *= sc;
      mreg = mn;
      scl[w][l31] = sc;
#pragma unroll
      for (int r = 0; r < 16; ++r) {
        const int il = (r & 3) + 8 * (r >> 2) + 4 * hi;
        const float scr = scl[w][il];
        o0[r] *= scr; o1[r] *= scr;
      }
    }

#pragma unroll
    for (int r = 0; r < 16; ++r) s[r] = fexp2(s[r] - mreg);
    {
      float l0 = (s[0] + s[4]) + (s[8] + s[12]);
      float l1 = (s[1] + s[5]) + (s[9] + s[13]);
      float l2 = (s[2] + s[6]) + (s[10] + s[14]);
      float l3 = (s[3] + s[7]) + (s[11] + s[15]);
      ls += (l0 + l1) + (l2 + l3);
    }

    f16x8 pfr[2];
    {
      unsigned a0 = pkf16(s[0], s[1]),  b0 = pkf16(s[4], s[5]);
      unsigned a1 = pkf16(s[2], s[3]),  b1 = pkf16(s[6], s[7]);
      plswap(a0, b0); plswap(a1, b1);
      u32x4 t; t[0] = a0; t[1] = a1; t[2] = b0; t[3] = b1;
      pfr[0] = __builtin_bit_cast(f16x8, t);
      unsigned a2 = pkf16(s[8], s[9]),   b2 = pkf16(s[12], s[13]);
      unsigned a3 = pkf16(s[10], s[11]), b3 = pkf16(s[14], s[15]);
      plswap(a2, b2); plswap(a3, b3);
      t[0] = a2; t[1] = a3; t[2] = b2; t[3] = b3;
      pfr[1] = __builtin_bit_cast(f16x8, t);
    }

    __builtin_amdgcn_s_setprio(1);
#pragma unroll
    for (int kk = 0; kk < 2; ++kk) {
      o0 = __builtin_amdgcn_mfma_f32_32x32x16_f16(pfr[kk], kt0[kk], o0, 0, 0, 0);
      o1 = __builtin_amdgcn_mfma_f32_32x32x16_f16(pfr[kk], kt1[kk], o1, 0, 0, 0);
    }
    __builtin_amdgcn_s_setprio(0);
  }

  // ---- flash merge of the two j-halves ----
  mM[i_sub][jh][l31]  = mreg;
  lsM[i_sub][jh][l31] = ls + __shfl_xor(ls, 32);
  __syncthreads();

  if (jh == 1) {
#pragma unroll
    for (int r = 0; r < 16; ++r) {
      const int il = (r & 3) + 8 * (r >> 2) + 4 * hi;
      const float mS = fmaxf(mM[i_sub][0][il], mM[i_sub][1][il]);
      const float f = fexp2(mM[i_sub][1][il] - mS);
      obuf[i_sub][r][lane]      = o0[r] * f;
      obuf[i_sub][r + 16][lane] = o1[r] * f;
    }
  }
  __syncthreads();
  if (jh == 0) {
#pragma unroll
    for (int r = 0; r < 16; ++r) {
      const int il = (r & 3) + 8 * (r >> 2) + 4 * hi;
      const float mA = mM[i_sub][0][il], mB = mM[i_sub][1][il];
      const float mS = fmaxf(mA, mB);
      const float fA = fexp2(mA - mS);
      const float fB = fexp2(mB - mS);
      const float lsS = lsM[i_sub][0][il] * fA + lsM[i_sub][1][il] * fB;
      const float inv = 1.0f / lsS;
      const size_t rowb = ((size_t)bh * NTOK + i0 + il) * HD;
      out[rowb + l31]      = (o0[r] * fA + obuf[i_sub][r][lane]) * inv;
      out[rowb + 32 + l31] = (o1[r] * fA + obuf[i_sub][r + 16][lane]) * inv;
    }
  }
}

extern "C" void kernel_launch(void* const* d_in, const int* in_sizes, int n_in,
                              void* d_out, int out_size, void* d_ws, size_t ws_size,
                              hipStream_t stream) {
  const float* x  = (const float*)d_in[0];
  const float* Wk = (const float*)d_in[1];
  const float* Wq = (const float*)d_in[2];
  // d_in[3] (Wv) is dead code in the reference — never read.
  float* out = (float*)d_out;

  // Preferred ws layout (f16 elems, 71.3 MB):
  //   xb[8388608] Wkb[1048576] Wqb[1048576] Kp[8388608] Qp[8388608] KTp[8388608]
  // Fallback (54.5 MB, r15 schedule): KTp aliases xb, separate pack_kt pass.
  _Float16* xb  = (_Float16*)d_ws;
  _Float16* Wkb = xb + (size_t)8388608;
  _Float16* Wqb = Wkb + (size_t)1048576;
  _Float16* Kp  = Wqb + (size_t)1048576;
  _Float16* Qp  = Kp + (size_t)8388608;
  const bool fuseKT = ws_size >= (size_t)71303168;
  _Float16* KTp = fuseKT ? (Qp + (size_t)8388608) : xb;

  cvt_all<<<10240, 256, 0, stream>>>(x, Wk, Wq, xb, Wkb, Wqb);

  dim3 ggrid(MROWS / 128, DMODEL / 128, 2);   // z=0 -> Kp(+KTp), z=1 -> Qp
  gemm_pack_f16<<<ggrid, 256, 0, stream>>>(xb, Wkb, Wqb, Kp, Qp, KTp,
                                           fuseKT ? 1 : 0);

  if (!fuseKT) pack_kt<<<2048, 256, 0, stream>>>(Kp, KTp);

  attn_mfma<<<2048, 256, 0, stream>>>(Kp, Qp, KTp, out);
}

// Round 20
// 165.654 us; speedup vs baseline: 1.0446x; 1.0141x over previous
//
#include <hip/hip_runtime.h>
#include <cstdint>
#include <cstddef>

#define NTOK 2048
#define DMODEL 1024
#define HD 64
#define MROWS 8192

using f16x8  = __attribute__((ext_vector_type(8))) _Float16;
using f16x4  = __attribute__((ext_vector_type(4))) _Float16;
using f32x4  = __attribute__((ext_vector_type(4))) float;
using f32x16 = __attribute__((ext_vector_type(16))) float;
using u32x4  = __attribute__((ext_vector_type(4))) unsigned int;

#define Z16 {0.f,0.f,0.f,0.f,0.f,0.f,0.f,0.f,0.f,0.f,0.f,0.f,0.f,0.f,0.f,0.f}

__device__ __forceinline__ unsigned pkf16(float a, float b) {
  return __builtin_bit_cast(unsigned, __builtin_amdgcn_cvt_pkrtz(a, b));
}
__device__ __forceinline__ void plswap(unsigned &a, unsigned &b) {
  auto r = __builtin_amdgcn_permlane32_swap(a, b, false, false);
  a = r[0]; b = r[1];
}
__device__ __forceinline__ float fexp2(float x) {
  return __builtin_amdgcn_exp2f(x);
}
__device__ __forceinline__ float fmax3(float a, float b, float c) {
  return fmaxf(fmaxf(a, b), c);
}

// ---------------------------------------------------------------------------
// Fused f32->f16 convert: blocks [0,8192) x; [8192,9216) Wk; [9216,10240) Wq
// (log2e folded into Wq).
// ---------------------------------------------------------------------------
__global__ __launch_bounds__(256) void cvt_all(const float* __restrict__ x,
                                               const float* __restrict__ Wk,
                                               const float* __restrict__ Wq,
                                               _Float16* __restrict__ xb,
                                               _Float16* __restrict__ Wkb,
                                               _Float16* __restrict__ Wqb) {
  const int blk = blockIdx.x;
  const float* in;
  _Float16* out;
  float scale;
  int idx;
  if (blk < 8192) {
    in = x; out = xb; scale = 1.0f;
    idx = blk * 256 + threadIdx.x;
  } else if (blk < 9216) {
    in = Wk; out = Wkb; scale = 1.0f;
    idx = (blk - 8192) * 256 + threadIdx.x;
  } else {
    in = Wq; out = Wqb; scale = 1.4426950408889634f;
    idx = (blk - 9216) * 256 + threadIdx.x;
  }
  float4 v = reinterpret_cast<const float4*>(in)[idx];
  f16x4 o;
  o.x = (_Float16)(v.x * scale); o.y = (_Float16)(v.y * scale);
  o.z = (_Float16)(v.z * scale); o.w = (_Float16)(v.w * scale);
  reinterpret_cast<f16x4*>(out)[idx] = o;
}

// ---------------------------------------------------------------------------
// f16 MFMA GEMM with FUSED PACK epilogue (r17, unchanged). z=0 -> Kp + KTp,
// z=1 -> Qp.
// ---------------------------------------------------------------------------
#define GLDS16(g, l) __builtin_amdgcn_global_load_lds(                      \
    (const __attribute__((address_space(1))) void*)(g),                     \
    (__attribute__((address_space(3))) void*)(l), 16, 0, 0)

__global__ __launch_bounds__(256) void gemm_pack_f16(
    const _Float16* __restrict__ X,
    const _Float16* __restrict__ Wk,
    const _Float16* __restrict__ Wq,
    _Float16* __restrict__ Kp,
    _Float16* __restrict__ Qp,
    _Float16* __restrict__ KTp,
    int emitKT) {
  const bool isQ = blockIdx.z != 0;
  const _Float16* __restrict__ W = isQ ? Wq : Wk;

  __shared__ _Float16 arena[17408];
  _Float16* As = arena;           // [2][4096]
  _Float16* Bs = arena + 8192;    // [2][4096]

  const int tid = threadIdx.x;
  const int lane = tid & 63;
  const int w = tid >> 6;
  const int m0 = blockIdx.x * 128;
  const int o0 = blockIdx.y * 128;

  const int srow = w * 32 + (lane >> 2);
  const int scol = (lane & 3) * 8;
  const _Float16* xsrc = X + (size_t)(m0 + srow) * DMODEL + scol;
  const _Float16* wsrc = W + (size_t)(o0 + srow) * DMODEL + scol;

  const int wr = w >> 1, wc = w & 1;
  const int arow = lane & 15, kg = lane >> 4;
  const int l31 = lane & 31, hi8 = (lane >> 5) * 8;

  f32x4 zero = {0.f, 0.f, 0.f, 0.f};
  f32x4 acc[4][4];
#pragma unroll
  for (int mi = 0; mi < 4; ++mi)
#pragma unroll
    for (int ni = 0; ni < 4; ++ni) acc[mi][ni] = zero;

  GLDS16(xsrc,               &As[(w * 32) * 32]);
  GLDS16(xsrc + 16 * DMODEL, &As[(w * 32 + 16) * 32]);
  GLDS16(wsrc,               &Bs[(w * 32) * 32]);
  GLDS16(wsrc + 16 * DMODEL, &Bs[(w * 32 + 16) * 32]);

  for (int kt = 0; kt < 32; ++kt) {
    __syncthreads();
    if (kt + 1 < 32) {
      const int ko = (kt + 1) * 32;
      const int bo = ((kt + 1) & 1) * 4096;
      GLDS16(xsrc + ko,               &As[bo + (w * 32) * 32]);
      GLDS16(xsrc + ko + 16 * DMODEL, &As[bo + (w * 32 + 16) * 32]);
      GLDS16(wsrc + ko,               &Bs[bo + (w * 32) * 32]);
      GLDS16(wsrc + ko + 16 * DMODEL, &Bs[bo + (w * 32 + 16) * 32]);
    }
    const int bo = (kt & 1) * 4096;
    f16x8 af[4], bfr[4];
#pragma unroll
    for (int mi = 0; mi < 4; ++mi)
      af[mi] = *reinterpret_cast<const f16x8*>(
          &As[bo + (wr * 64 + mi * 16 + arow) * 32 + kg * 8]);
#pragma unroll
    for (int ni = 0; ni < 4; ++ni)
      bfr[ni] = *reinterpret_cast<const f16x8*>(
          &Bs[bo + (wc * 64 + ni * 16 + arow) * 32 + kg * 8]);
#pragma unroll
    for (int mi = 0; mi < 4; ++mi)
#pragma unroll
      for (int ni = 0; ni < 4; ++ni)
        acc[mi][ni] = __builtin_amdgcn_mfma_f32_16x16x32_f16(
            af[mi], bfr[ni], acc[mi][ni], 0, 0, 0);
  }

  __syncthreads();
  _Float16* T = arena;             // [128][136]
#pragma unroll
  for (int mi = 0; mi < 4; ++mi)
#pragma unroll
    for (int ni = 0; ni < 4; ++ni)
#pragma unroll
      for (int r = 0; r < 4; ++r)
        T[(wr * 64 + mi * 16 + kg * 4 + r) * 136 + wc * 64 + ni * 16 + arow] =
            (_Float16)acc[mi][ni][r];
  __syncthreads();

  const int b = m0 >> 11;
  _Float16* RowDst = isQ ? Qp : Kp;
#pragma unroll
  for (int k = 0; k < 8; ++k) {
    const int c = w * 8 + k;
    const int hl = c >> 4, rtl = (c >> 2) & 3, ks = c & 3;
    f16x8 v = *reinterpret_cast<const f16x8*>(
        &T[(rtl * 32 + l31) * 136 + hl * 64 + ks * 16 + hi8]);
    const int bh = b * 16 + (o0 >> 6) + hl;
    const int rt = ((m0 & 2047) >> 5) + rtl;
    const size_t ch = ((size_t)(bh * 64 + rt) * 4 + ks) * 512 + (size_t)lane * 8;
    *reinterpret_cast<f16x8*>(&RowDst[ch]) = v;
  }

  if (!isQ && emitKT) {
#pragma unroll
    for (int k = 0; k < 8; ++k) {
      const int c = w * 8 + k;                 // (hl, jtl, ds, ks)
      const int hl = c >> 4, jtl = (c >> 3) & 1, ds = (c >> 2) & 1, ks = c & 3;
      const int row0 = jtl * 64 + ks * 16 + (lane >> 5) * 8;
      const int col = hl * 64 + ds * 32 + l31;
      f16x8 v;
#pragma unroll
      for (int e = 0; e < 8; ++e) v[e] = T[(row0 + e) * 136 + col];
      const int bh = b * 16 + (o0 >> 6) + hl;
      const int jt = ((m0 & 2047) >> 6) + jtl;
      const size_t ch =
          (((size_t)(bh * 32 + jt) * 2 + ds) * 4 + ks) * 512 + (size_t)lane * 8;
      *reinterpret_cast<f16x8*>(&KTp[ch]) = v;
    }
  }
}

// ---------------------------------------------------------------------------
// pack_kt (fallback when ws too small to give KTp its own region)
// ---------------------------------------------------------------------------
__global__ __launch_bounds__(256) void pack_kt(
    const _Float16* __restrict__ Kp,
    _Float16* __restrict__ KTp) {
  const int blk = blockIdx.x;
  const int bh = blk >> 5;
  const int t64 = blk & 31;
  const int tid = threadIdx.x;
  const int l = tid & 63;

  __shared__ _Float16 t[64][72];
#pragma unroll
  for (int pass = 0; pass < 2; ++pass) {
    const int idx = pass * 4 + (tid >> 6);
    const int rs = idx >> 2, ks = idx & 3;
    f16x8 v = *reinterpret_cast<const f16x8*>(
        &Kp[((size_t)(bh * 64 + t64 * 2 + rs) * 4 + ks) * 512 + (size_t)l * 8]);
    *reinterpret_cast<f16x8*>(&t[rs * 32 + (l & 31)][ks * 16 + (l >> 5) * 8]) = v;
  }
  __syncthreads();
#pragma unroll
  for (int pass = 0; pass < 2; ++pass) {
    const int idx = pass * 4 + (tid >> 6);
    const int ds = idx >> 2, ks = idx & 3;
    const int row0 = ks * 16 + (l >> 5) * 8;
    const int col = ds * 32 + (l & 31);
    f16x8 v;
#pragma unroll
    for (int e = 0; e < 8; ++e) v[e] = t[row0 + e][col];
    const size_t ch = (((size_t)(bh * 32 + t64) * 2 + ds) * 4 + ks) * 512 + (size_t)l * 8;
    *reinterpret_cast<f16x8*>(&KTp[ch]) = v;
  }
}

// ---------------------------------------------------------------------------
// Swapped-operand MFMA flash attention, SPLIT-J, with PING-PONG PREFETCH.
// r19 cycle accounting: ~1035 cyc/tile/SIMD at 3 waves = ~3100 cyc serial
// chain per wave-tile, vs ~400 cyc static compute -> the chain is dominated
// by q/kt L2/L3 load latency issued at tile top. Fix: named A/B register
// sets (static-indexed, rule #20); tile t+1's 8 loads issue before tile t's
// softmax+PV, hiding the round trip under ~1000 cyc of compute. +32 regs,
// inside the (256,3) ceiling (r9's +2% attempt ran register-starved; the
// post-r12 lean structure has the headroom this needs).
// ---------------------------------------------------------------------------
__global__ __launch_bounds__(256, 3) void attn_mfma(
    const _Float16* __restrict__ Kp,
    const _Float16* __restrict__ Qp,
    const _Float16* __restrict__ KTp,
    float* __restrict__ out) {
  const int bid = blockIdx.x;
  const int myid = (bid & 7) * 256 + (bid >> 3);   // 2048 blocks, bijective
  const int bh = myid >> 5;                        // 32 blocks per head
  const int itile = myid & 31;
  const int tid = threadIdx.x, lane = tid & 63, w = tid >> 6;
  const int l31 = lane & 31;
  const int hi = lane >> 5;
  const int i_sub = w & 1;
  const int jh = w >> 1;
  const int i0 = itile * 64 + i_sub * 32;

  const _Float16* kpp  = Kp  + (size_t)bh * 131072 + lane * 8;
  const _Float16* qpp  = Qp  + (size_t)bh * 131072 + lane * 8;
  const _Float16* ktpp = KTp + (size_t)bh * 131072 + lane * 8;

  __shared__ float scl[4][32];
  __shared__ float mM[2][2][32];
  __shared__ float lsM[2][2][32];
  __shared__ float obuf[2][32][64];

  f16x8 kbf[4];
#pragma unroll
  for (int ks = 0; ks < 4; ++ks)
    kbf[ks] = *reinterpret_cast<const f16x8*>(
        kpp + ((size_t)(i0 >> 5) * 4 + ks) * 512);

  const f32x16 z16v = Z16;
  f32x16 o0 = z16v, o1 = z16v;
  float mreg = -1e30f, ls = 0.f;

  const int jt0 = jh * 32;

  f16x8 qA[4], qB[4], ktA0[2], ktA1[2], ktB0[2], ktB1[2];

#define LOADT(QD, KT0, KT1, JT)                                               \
  {                                                                           \
    _Pragma("unroll")                                                         \
    for (int ks = 0; ks < 4; ++ks)                                            \
      QD[ks] = *reinterpret_cast<const f16x8*>(                               \
          qpp + ((size_t)(JT) * 4 + ks) * 512);                               \
    const size_t base =                                                       \
        ((size_t)((JT) >> 1) * 8 + (size_t)((JT) & 1) * 2) * 512;             \
    KT0[0] = *reinterpret_cast<const f16x8*>(ktpp + base);                    \
    KT0[1] = *reinterpret_cast<const f16x8*>(ktpp + base + 512);              \
    KT1[0] = *reinterpret_cast<const f16x8*>(ktpp + base + 2048);             \
    KT1[1] = *reinterpret_cast<const f16x8*>(ktpp + base + 2560);             \
  }

#define PROC(Q, KT0, KT1)                                                     \
  {                                                                           \
    f32x16 s = z16v;                                                          \
    __builtin_amdgcn_s_setprio(1);                                            \
    _Pragma("unroll")                                                         \
    for (int ks = 0; ks < 4; ++ks)                                            \
      s = __builtin_amdgcn_mfma_f32_32x32x16_f16(Q[ks], kbf[ks], s, 0, 0, 0); \
    __builtin_amdgcn_s_setprio(0);                                            \
    float t0 = fmax3(s[0], s[1], s[2]);                                       \
    float t1 = fmax3(s[3], s[4], s[5]);                                       \
    float t2 = fmax3(s[6], s[7], s[8]);                                       \
    float t3 = fmax3(s[9], s[10], s[11]);                                     \
    float t4 = fmax3(s[12], s[13], s[14]);                                    \
    float pm = fmaxf(fmax3(t0, t1, t2), fmax3(t3, t4, s[15]));                \
    pm = fmaxf(pm, __shfl_xor(pm, 32));                                       \
    if (!__all(pm <= mreg + 8.0f)) {                                          \
      const float mn = fmaxf(mreg, pm);                                       \
      const float sc = fexp2(mreg - mn);                                      \
      ls *= sc;                                                               \
      mreg = mn;                                                              \
      scl[w][l31] = sc;                                                       \
      _Pragma("unroll")                                                       \
      for (int r = 0; r < 16; ++r) {                                          \
        const int il = (r & 3) + 8 * (r >> 2) + 4 * hi;                       \
        const float scr = scl[w][il];                                         \
        o0[r] *= scr; o1[r] *= scr;                                           \
      }                                                                       \
    }                                                                         \
    _Pragma("unroll")                                                         \
    for (int r = 0; r < 16; ++r) s[r] = fexp2(s[r] - mreg);                   \
    {                                                                         \
      float l0 = (s[0] + s[4]) + (s[8] + s[12]);                              \
      float l1 = (s[1] + s[5]) + (s[9] + s[13]);                              \
      float l2 = (s[2] + s[6]) + (s[10] + s[14]);                             \
      float l3 = (s[3] + s[7]) + (s[11] + s[15]);                             \
      ls += (l0 + l1) + (l2 + l3);                                            \
    }                                                                         \
    f16x8 pfr[2];                                                             \
    {                                                                         \
      unsigned a0 = pkf16(s[0], s[1]),  b0 = pkf16(s[4], s[5]);               \
      unsigned a1 = pkf16(s[2], s[3]),  b1 = pkf16(s[6], s[7]);               \
      plswap(a0, b0); plswap(a1, b1);                                         \
      u32x4 t; t[0] = a0; t[1] = a1; t[2] = b0; t[3] = b1;                    \
      pfr[0] = __builtin_bit_cast(f16x8, t);                                  \
      unsigned a2 = pkf16(s[8], s[9]),   b2 = pkf16(s[12], s[13]);            \
      unsigned a3 = pkf16(s[10], s[11]), b3 = pkf16(s[14], s[15]);            \
      plswap(a2, b2); plswap(a3, b3);                                         \
      t[0] = a2; t[1] = a3; t[2] = b2; t[3] = b3;                             \
      pfr[1] = __builtin_bit_cast(f16x8, t);                                  \
    }                                                                         \
    __builtin_amdgcn_s_setprio(1);                                            \
    _Pragma("unroll")                                                         \
    for (int kk = 0; kk < 2; ++kk) {                                          \
      o0 = __builtin_amdgcn_mfma_f32_32x32x16_f16(pfr[kk], KT0[kk], o0, 0,0,0);\
      o1 = __builtin_amdgcn_mfma_f32_32x32x16_f16(pfr[kk], KT1[kk], o1, 0,0,0);\
    }                                                                         \
    __builtin_amdgcn_s_setprio(0);                                            \
  }

  LOADT(qA, ktA0, ktA1, jt0)
  for (int it = 0; it < 16; ++it) {
    const int jtA = jt0 + it * 2;
    LOADT(qB, ktB0, ktB1, jtA + 1)
    PROC(qA, ktA0, ktA1)
    if (it < 15) LOADT(qA, ktA0, ktA1, jtA + 2)
    PROC(qB, ktB0, ktB1)
  }
#undef LOADT
#undef PROC

  // ---- flash merge of the two j-halves ----
  mM[i_sub][jh][l31]  = mreg;
  lsM[i_sub][jh][l31] = ls + __shfl_xor(ls, 32);
  __syncthreads();

  if (jh == 1) {
#pragma unroll
    for (int r = 0; r < 16; ++r) {
      const int il = (r & 3) + 8 * (r >> 2) + 4 * hi;
      const float mS = fmaxf(mM[i_sub][0][il], mM[i_sub][1][il]);
      const float f = fexp2(mM[i_sub][1][il] - mS);
      obuf[i_sub][r][lane]      = o0[r] * f;
      obuf[i_sub][r + 16][lane] = o1[r] * f;
    }
  }
  __syncthreads();
  if (jh == 0) {
#pragma unroll
    for (int r = 0; r < 16; ++r) {
      const int il = (r & 3) + 8 * (r >> 2) + 4 * hi;
      const float mA = mM[i_sub][0][il], mB = mM[i_sub][1][il];
      const float mS = fmaxf(mA, mB);
      const float fA = fexp2(mA - mS);
      const float fB = fexp2(mB - mS);
      const float lsS = lsM[i_sub][0][il] * fA + lsM[i_sub][1][il] * fB;
      const float inv = 1.0f / lsS;
      const size_t rowb = ((size_t)bh * NTOK + i0 + il) * HD;
      out[rowb + l31]      = (o0[r] * fA + obuf[i_sub][r][lane]) * inv;
      out[rowb + 32 + l31] = (o1[r] * fA + obuf[i_sub][r + 16][lane]) * inv;
    }
  }
}

extern "C" void kernel_launch(void* const* d_in, const int* in_sizes, int n_in,
                              void* d_out, int out_size, void* d_ws, size_t ws_size,
                              hipStream_t stream) {
  const float* x  = (const float*)d_in[0];
  const float* Wk = (const float*)d_in[1];
  const float* Wq = (const float*)d_in[2];
  // d_in[3] (Wv) is dead code in the reference — never read.
  float* out = (float*)d_out;

  // Preferred ws layout (f16 elems, 71.3 MB):
  //   xb[8388608] Wkb[1048576] Wqb[1048576] Kp[8388608] Qp[8388608] KTp[8388608]
  // Fallback (54.5 MB): KTp aliases xb, separate pack_kt pass.
  _Float16* xb  = (_Float16*)d_ws;
  _Float16* Wkb = xb + (size_t)8388608;
  _Float16* Wqb = Wkb + (size_t)1048576;
  _Float16* Kp  = Wqb + (size_t)1048576;
  _Float16* Qp  = Kp + (size_t)8388608;
  const bool fuseKT = ws_size >= (size_t)71303168;
  _Float16* KTp = fuseKT ? (Qp + (size_t)8388608) : xb;

  cvt_all<<<10240, 256, 0, stream>>>(x, Wk, Wq, xb, Wkb, Wqb);

  dim3 ggrid(MROWS / 128, DMODEL / 128, 2);   // z=0 -> Kp(+KTp), z=1 -> Qp
  gemm_pack_f16<<<ggrid, 256, 0, stream>>>(xb, Wkb, Wqb, Kp, Qp, KTp,
                                           fuseKT ? 1 : 0);

  if (!fuseKT) pack_kt<<<2048, 256, 0, stream>>>(Kp, KTp);

  attn_mfma<<<2048, 256, 0, stream>>>(Kp, Qp, KTp, out);
}

// Round 21
// 165.611 us; speedup vs baseline: 1.0449x; 1.0003x over previous
//
#include <hip/hip_runtime.h>
#include <cstdint>
#include <cstddef>

#define NTOK 2048
#define DMODEL 1024
#define HD 64
#define MROWS 8192

using f16x8  = __attribute__((ext_vector_type(8))) _Float16;
using f16x4  = __attribute__((ext_vector_type(4))) _Float16;
using f32x4  = __attribute__((ext_vector_type(4))) float;
using f32x16 = __attribute__((ext_vector_type(16))) float;
using u32x4  = __attribute__((ext_vector_type(4))) unsigned int;

#define Z16 {0.f,0.f,0.f,0.f,0.f,0.f,0.f,0.f,0.f,0.f,0.f,0.f,0.f,0.f,0.f,0.f}

__device__ __forceinline__ unsigned pkf16(float a, float b) {
  return __builtin_bit_cast(unsigned, __builtin_amdgcn_cvt_pkrtz(a, b));
}
__device__ __forceinline__ void plswap(unsigned &a, unsigned &b) {
  auto r = __builtin_amdgcn_permlane32_swap(a, b, false, false);
  a = r[0]; b = r[1];
}
__device__ __forceinline__ float fexp2(float x) {
  return __builtin_amdgcn_exp2f(x);
}
__device__ __forceinline__ float fmax3(float a, float b, float c) {
  return fmaxf(fmaxf(a, b), c);
}

// ---------------------------------------------------------------------------
// Fused f32->f16 convert: blocks [0,8192) x; [8192,9216) Wk; [9216,10240) Wq
// (log2e folded into Wq).
// ---------------------------------------------------------------------------
__global__ __launch_bounds__(256) void cvt_all(const float* __restrict__ x,
                                               const float* __restrict__ Wk,
                                               const float* __restrict__ Wq,
                                               _Float16* __restrict__ xb,
                                               _Float16* __restrict__ Wkb,
                                               _Float16* __restrict__ Wqb) {
  const int blk = blockIdx.x;
  const float* in;
  _Float16* out;
  float scale;
  int idx;
  if (blk < 8192) {
    in = x; out = xb; scale = 1.0f;
    idx = blk * 256 + threadIdx.x;
  } else if (blk < 9216) {
    in = Wk; out = Wkb; scale = 1.0f;
    idx = (blk - 8192) * 256 + threadIdx.x;
  } else {
    in = Wq; out = Wqb; scale = 1.4426950408889634f;
    idx = (blk - 9216) * 256 + threadIdx.x;
  }
  float4 v = reinterpret_cast<const float4*>(in)[idx];
  f16x4 o;
  o.x = (_Float16)(v.x * scale); o.y = (_Float16)(v.y * scale);
  o.z = (_Float16)(v.z * scale); o.w = (_Float16)(v.w * scale);
  reinterpret_cast<f16x4*>(out)[idx] = o;
}

// ---------------------------------------------------------------------------
// f16 MFMA GEMM with FUSED PACK epilogue (r17, unchanged). z=0 -> Kp + KTp,
// z=1 -> Qp.
// ---------------------------------------------------------------------------
#define GLDS16(g, l) __builtin_amdgcn_global_load_lds(                      \
    (const __attribute__((address_space(1))) void*)(g),                     \
    (__attribute__((address_space(3))) void*)(l), 16, 0, 0)

__global__ __launch_bounds__(256) void gemm_pack_f16(
    const _Float16* __restrict__ X,
    const _Float16* __restrict__ Wk,
    const _Float16* __restrict__ Wq,
    _Float16* __restrict__ Kp,
    _Float16* __restrict__ Qp,
    _Float16* __restrict__ KTp,
    int emitKT) {
  const bool isQ = blockIdx.z != 0;
  const _Float16* __restrict__ W = isQ ? Wq : Wk;

  __shared__ _Float16 arena[17408];
  _Float16* As = arena;           // [2][4096]
  _Float16* Bs = arena + 8192;    // [2][4096]

  const int tid = threadIdx.x;
  const int lane = tid & 63;
  const int w = tid >> 6;
  const int m0 = blockIdx.x * 128;
  const int o0 = blockIdx.y * 128;

  const int srow = w * 32 + (lane >> 2);
  const int scol = (lane & 3) * 8;
  const _Float16* xsrc = X + (size_t)(m0 + srow) * DMODEL + scol;
  const _Float16* wsrc = W + (size_t)(o0 + srow) * DMODEL + scol;

  const int wr = w >> 1, wc = w & 1;
  const int arow = lane & 15, kg = lane >> 4;
  const int l31 = lane & 31, hi8 = (lane >> 5) * 8;

  f32x4 zero = {0.f, 0.f, 0.f, 0.f};
  f32x4 acc[4][4];
#pragma unroll
  for (int mi = 0; mi < 4; ++mi)
#pragma unroll
    for (int ni = 0; ni < 4; ++ni) acc[mi][ni] = zero;

  GLDS16(xsrc,               &As[(w * 32) * 32]);
  GLDS16(xsrc + 16 * DMODEL, &As[(w * 32 + 16) * 32]);
  GLDS16(wsrc,               &Bs[(w * 32) * 32]);
  GLDS16(wsrc + 16 * DMODEL, &Bs[(w * 32 + 16) * 32]);

  for (int kt = 0; kt < 32; ++kt) {
    __syncthreads();
    if (kt + 1 < 32) {
      const int ko = (kt + 1) * 32;
      const int bo = ((kt + 1) & 1) * 4096;
      GLDS16(xsrc + ko,               &As[bo + (w * 32) * 32]);
      GLDS16(xsrc + ko + 16 * DMODEL, &As[bo + (w * 32 + 16) * 32]);
      GLDS16(wsrc + ko,               &Bs[bo + (w * 32) * 32]);
      GLDS16(wsrc + ko + 16 * DMODEL, &Bs[bo + (w * 32 + 16) * 32]);
    }
    const int bo = (kt & 1) * 4096;
    f16x8 af[4], bfr[4];
#pragma unroll
    for (int mi = 0; mi < 4; ++mi)
      af[mi] = *reinterpret_cast<const f16x8*>(
          &As[bo + (wr * 64 + mi * 16 + arow) * 32 + kg * 8]);
#pragma unroll
    for (int ni = 0; ni < 4; ++ni)
      bfr[ni] = *reinterpret_cast<const f16x8*>(
          &Bs[bo + (wc * 64 + ni * 16 + arow) * 32 + kg * 8]);
#pragma unroll
    for (int mi = 0; mi < 4; ++mi)
#pragma unroll
      for (int ni = 0; ni < 4; ++ni)
        acc[mi][ni] = __builtin_amdgcn_mfma_f32_16x16x32_f16(
            af[mi], bfr[ni], acc[mi][ni], 0, 0, 0);
  }

  __syncthreads();
  _Float16* T = arena;             // [128][136]
#pragma unroll
  for (int mi = 0; mi < 4; ++mi)
#pragma unroll
    for (int ni = 0; ni < 4; ++ni)
#pragma unroll
      for (int r = 0; r < 4; ++r)
        T[(wr * 64 + mi * 16 + kg * 4 + r) * 136 + wc * 64 + ni * 16 + arow] =
            (_Float16)acc[mi][ni][r];
  __syncthreads();

  const int b = m0 >> 11;
  _Float16* RowDst = isQ ? Qp : Kp;
#pragma unroll
  for (int k = 0; k < 8; ++k) {
    const int c = w * 8 + k;
    const int hl = c >> 4, rtl = (c >> 2) & 3, ks = c & 3;
    f16x8 v = *reinterpret_cast<const f16x8*>(
        &T[(rtl * 32 + l31) * 136 + hl * 64 + ks * 16 + hi8]);
    const int bh = b * 16 + (o0 >> 6) + hl;
    const int rt = ((m0 & 2047) >> 5) + rtl;
    const size_t ch = ((size_t)(bh * 64 + rt) * 4 + ks) * 512 + (size_t)lane * 8;
    *reinterpret_cast<f16x8*>(&RowDst[ch]) = v;
  }

  if (!isQ && emitKT) {
#pragma unroll
    for (int k = 0; k < 8; ++k) {
      const int c = w * 8 + k;                 // (hl, jtl, ds, ks)
      const int hl = c >> 4, jtl = (c >> 3) & 1, ds = (c >> 2) & 1, ks = c & 3;
      const int row0 = jtl * 64 + ks * 16 + (lane >> 5) * 8;
      const int col = hl * 64 + ds * 32 + l31;
      f16x8 v;
#pragma unroll
      for (int e = 0; e < 8; ++e) v[e] = T[(row0 + e) * 136 + col];
      const int bh = b * 16 + (o0 >> 6) + hl;
      const int jt = ((m0 & 2047) >> 6) + jtl;
      const size_t ch =
          (((size_t)(bh * 32 + jt) * 2 + ds) * 4 + ks) * 512 + (size_t)lane * 8;
      *reinterpret_cast<f16x8*>(&KTp[ch]) = v;
    }
  }
}

// ---------------------------------------------------------------------------
// pack_kt (fallback when ws too small to give KTp its own region)
// ---------------------------------------------------------------------------
__global__ __launch_bounds__(256) void pack_kt(
    const _Float16* __restrict__ Kp,
    _Float16* __restrict__ KTp) {
  const int blk = blockIdx.x;
  const int bh = blk >> 5;
  const int t64 = blk & 31;
  const int tid = threadIdx.x;
  const int l = tid & 63;

  __shared__ _Float16 t[64][72];
#pragma unroll
  for (int pass = 0; pass < 2; ++pass) {
    const int idx = pass * 4 + (tid >> 6);
    const int rs = idx >> 2, ks = idx & 3;
    f16x8 v = *reinterpret_cast<const f16x8*>(
        &Kp[((size_t)(bh * 64 + t64 * 2 + rs) * 4 + ks) * 512 + (size_t)l * 8]);
    *reinterpret_cast<f16x8*>(&t[rs * 32 + (l & 31)][ks * 16 + (l >> 5) * 8]) = v;
  }
  __syncthreads();
#pragma unroll
  for (int pass = 0; pass < 2; ++pass) {
    const int idx = pass * 4 + (tid >> 6);
    const int ds = idx >> 2, ks = idx & 3;
    const int row0 = ks * 16 + (l >> 5) * 8;
    const int col = ds * 32 + (l & 31);
    f16x8 v;
#pragma unroll
    for (int e = 0; e < 8; ++e) v[e] = t[row0 + e][col];
    const size_t ch = (((size_t)(bh * 32 + t64) * 2 + ds) * 4 + ks) * 512 + (size_t)l * 8;
    *reinterpret_cast<f16x8*>(&KTp[ch]) = v;
  }
}

// ---------------------------------------------------------------------------
// Swapped-operand MFMA flash attention, SPLIT-J, BALANCED PREFETCH:
// r20 showed full (Q+KT) ping-pong gains ILP but drops occupancy to ~27%
// (+64 regs). Balanced version: Q keeps the 1-deep named ping-pong (it heads
// the dependency chain into QK), KT returns to the tile body issued right
// after the QK MFMAs (~250 cyc ahead of PV use, covered by softmax VALU —
// the r19 placement). -32 regs vs r20 -> 3 waves/SIMD + Q-ILP together.
// ---------------------------------------------------------------------------
__global__ __launch_bounds__(256, 3) void attn_mfma(
    const _Float16* __restrict__ Kp,
    const _Float16* __restrict__ Qp,
    const _Float16* __restrict__ KTp,
    float* __restrict__ out) {
  const int bid = blockIdx.x;
  const int myid = (bid & 7) * 256 + (bid >> 3);   // 2048 blocks, bijective
  const int bh = myid >> 5;                        // 32 blocks per head
  const int itile = myid & 31;
  const int tid = threadIdx.x, lane = tid & 63, w = tid >> 6;
  const int l31 = lane & 31;
  const int hi = lane >> 5;
  const int i_sub = w & 1;
  const int jh = w >> 1;
  const int i0 = itile * 64 + i_sub * 32;

  const _Float16* kpp  = Kp  + (size_t)bh * 131072 + lane * 8;
  const _Float16* qpp  = Qp  + (size_t)bh * 131072 + lane * 8;
  const _Float16* ktpp = KTp + (size_t)bh * 131072 + lane * 8;

  __shared__ float scl[4][32];
  __shared__ float mM[2][2][32];
  __shared__ float lsM[2][2][32];
  __shared__ float obuf[2][32][64];

  f16x8 kbf[4];
#pragma unroll
  for (int ks = 0; ks < 4; ++ks)
    kbf[ks] = *reinterpret_cast<const f16x8*>(
        kpp + ((size_t)(i0 >> 5) * 4 + ks) * 512);

  const f32x16 z16v = Z16;
  f32x16 o0 = z16v, o1 = z16v;
  float mreg = -1e30f, ls = 0.f;

  const int jt0 = jh * 32;

  f16x8 qA[4], qB[4];

#define LOADQ(QD, JT)                                                         \
  {                                                                           \
    _Pragma("unroll")                                                         \
    for (int ks = 0; ks < 4; ++ks)                                            \
      QD[ks] = *reinterpret_cast<const f16x8*>(                               \
          qpp + ((size_t)(JT) * 4 + ks) * 512);                               \
  }

#define PROC(Q, JT)                                                           \
  {                                                                           \
    f32x16 s = z16v;                                                          \
    __builtin_amdgcn_s_setprio(1);                                            \
    _Pragma("unroll")                                                         \
    for (int ks = 0; ks < 4; ++ks)                                            \
      s = __builtin_amdgcn_mfma_f32_32x32x16_f16(Q[ks], kbf[ks], s, 0, 0, 0); \
    __builtin_amdgcn_s_setprio(0);                                            \
    f16x8 kt0[2], kt1[2];                                                     \
    {                                                                         \
      const size_t base =                                                     \
          ((size_t)((JT) >> 1) * 8 + (size_t)((JT) & 1) * 2) * 512;           \
      kt0[0] = *reinterpret_cast<const f16x8*>(ktpp + base);                  \
      kt0[1] = *reinterpret_cast<const f16x8*>(ktpp + base + 512);            \
      kt1[0] = *reinterpret_cast<const f16x8*>(ktpp + base + 2048);           \
      kt1[1] = *reinterpret_cast<const f16x8*>(ktpp + base + 2560);           \
    }                                                                         \
    float t0 = fmax3(s[0], s[1], s[2]);                                       \
    float t1 = fmax3(s[3], s[4], s[5]);                                       \
    float t2 = fmax3(s[6], s[7], s[8]);                                       \
    float t3 = fmax3(s[9], s[10], s[11]);                                     \
    float t4 = fmax3(s[12], s[13], s[14]);                                    \
    float pm = fmaxf(fmax3(t0, t1, t2), fmax3(t3, t4, s[15]));                \
    pm = fmaxf(pm, __shfl_xor(pm, 32));                                       \
    if (!__all(pm <= mreg + 8.0f)) {                                          \
      const float mn = fmaxf(mreg, pm);                                       \
      const float sc = fexp2(mreg - mn);                                      \
      ls *= sc;                                                               \
      mreg = mn;                                                              \
      scl[w][l31] = sc;                                                       \
      _Pragma("unroll")                                                       \
      for (int r = 0; r < 16; ++r) {                                          \
        const int il = (r & 3) + 8 * (r >> 2) + 4 * hi;                       \
        const float scr = scl[w][il];                                         \
        o0[r] *= scr; o1[r] *= scr;                                           \
      }                                                                       \
    }                                                                         \
    _Pragma("unroll")                                                         \
    for (int r = 0; r < 16; ++r) s[r] = fexp2(s[r] - mreg);                   \
    {                                                                         \
      float l0 = (s[0] + s[4]) + (s[8] + s[12]);                              \
      float l1 = (s[1] + s[5]) + (s[9] + s[13]);                              \
      float l2 = (s[2] + s[6]) + (s[10] + s[14]);                             \
      float l3 = (s[3] + s[7]) + (s[11] + s[15]);                             \
      ls += (l0 + l1) + (l2 + l3);                                            \
    }                                                                         \
    f16x8 pfr[2];                                                             \
    {                                                                         \
      unsigned a0 = pkf16(s[0], s[1]),  b0 = pkf16(s[4], s[5]);               \
      unsigned a1 = pkf16(s[2], s[3]),  b1 = pkf16(s[6], s[7]);               \
      plswap(a0, b0); plswap(a1, b1);                                         \
      u32x4 t; t[0] = a0; t[1] = a1; t[2] = b0; t[3] = b1;                    \
      pfr[0] = __builtin_bit_cast(f16x8, t);                                  \
      unsigned a2 = pkf16(s[8], s[9]),   b2 = pkf16(s[12], s[13]);            \
      unsigned a3 = pkf16(s[10], s[11]), b3 = pkf16(s[14], s[15]);            \
      plswap(a2, b2); plswap(a3, b3);                                         \
      t[0] = a2; t[1] = a3; t[2] = b2; t[3] = b3;                             \
      pfr[1] = __builtin_bit_cast(f16x8, t);                                  \
    }                                                                         \
    __builtin_amdgcn_s_setprio(1);                                            \
    _Pragma("unroll")                                                         \
    for (int kk = 0; kk < 2; ++kk) {                                          \
      o0 = __builtin_amdgcn_mfma_f32_32x32x16_f16(pfr[kk], kt0[kk], o0, 0,0,0);\
      o1 = __builtin_amdgcn_mfma_f32_32x32x16_f16(pfr[kk], kt1[kk], o1, 0,0,0);\
    }                                                                         \
    __builtin_amdgcn_s_setprio(0);                                            \
  }

  LOADQ(qA, jt0)
  for (int it = 0; it < 16; ++it) {
    const int jtA = jt0 + it * 2;
    LOADQ(qB, jtA + 1)
    PROC(qA, jtA)
    if (it < 15) LOADQ(qA, jtA + 2)
    PROC(qB, jtA + 1)
  }
#undef LOADQ
#undef PROC

  // ---- flash merge of the two j-halves ----
  mM[i_sub][jh][l31]  = mreg;
  lsM[i_sub][jh][l31] = ls + __shfl_xor(ls, 32);
  __syncthreads();

  if (jh == 1) {
#pragma unroll
    for (int r = 0; r < 16; ++r) {
      const int il = (r & 3) + 8 * (r >> 2) + 4 * hi;
      const float mS = fmaxf(mM[i_sub][0][il], mM[i_sub][1][il]);
      const float f = fexp2(mM[i_sub][1][il] - mS);
      obuf[i_sub][r][lane]      = o0[r] * f;
      obuf[i_sub][r + 16][lane] = o1[r] * f;
    }
  }
  __syncthreads();
  if (jh == 0) {
#pragma unroll
    for (int r = 0; r < 16; ++r) {
      const int il = (r & 3) + 8 * (r >> 2) + 4 * hi;
      const float mA = mM[i_sub][0][il], mB = mM[i_sub][1][il];
      const float mS = fmaxf(mA, mB);
      const float fA = fexp2(mA - mS);
      const float fB = fexp2(mB - mS);
      const float lsS = lsM[i_sub][0][il] * fA + lsM[i_sub][1][il] * fB;
      const float inv = 1.0f / lsS;
      const size_t rowb = ((size_t)bh * NTOK + i0 + il) * HD;
      out[rowb + l31]      = (o0[r] * fA + obuf[i_sub][r][lane]) * inv;
      out[rowb + 32 + l31] = (o1[r] * fA + obuf[i_sub][r + 16][lane]) * inv;
    }
  }
}

extern "C" void kernel_launch(void* const* d_in, const int* in_sizes, int n_in,
                              void* d_out, int out_size, void* d_ws, size_t ws_size,
                              hipStream_t stream) {
  const float* x  = (const float*)d_in[0];
  const float* Wk = (const float*)d_in[1];
  const float* Wq = (const float*)d_in[2];
  // d_in[3] (Wv) is dead code in the reference — never read.
  float* out = (float*)d_out;

  // Preferred ws layout (f16 elems, 71.3 MB):
  //   xb[8388608] Wkb[1048576] Wqb[1048576] Kp[8388608] Qp[8388608] KTp[8388608]
  // Fallback (54.5 MB): KTp aliases xb, separate pack_kt pass.
  _Float16* xb  = (_Float16*)d_ws;
  _Float16* Wkb = xb + (size_t)8388608;
  _Float16* Wqb = Wkb + (size_t)1048576;
  _Float16* Kp  = Wqb + (size_t)1048576;
  _Float16* Qp  = Kp + (size_t)8388608;
  const bool fuseKT = ws_size >= (size_t)71303168;
  _Float16* KTp = fuseKT ? (Qp + (size_t)8388608) : xb;

  cvt_all<<<10240, 256, 0, stream>>>(x, Wk, Wq, xb, Wkb, Wqb);

  dim3 ggrid(MROWS / 128, DMODEL / 128, 2);   // z=0 -> Kp(+KTp), z=1 -> Qp
  gemm_pack_f16<<<ggrid, 256, 0, stream>>>(xb, Wkb, Wqb, Kp, Qp, KTp,
                                           fuseKT ? 1 : 0);

  if (!fuseKT) pack_kt<<<2048, 256, 0, stream>>>(Kp, KTp);

  attn_mfma<<<2048, 256, 0, stream>>>(Kp, Qp, KTp, out);
}